// Round 1
// 315.170 us; speedup vs baseline: 1.0001x; 1.0001x over previous
//
#include <hip/hip_runtime.h>

#define CCH   255        // NB * SKIPC
#define SKIPC 85
#define WW    76
#define HWSZ  5776       // 76*76
#define THW   16         // hw positions per block tile (5776 = 361*16)
#define NBX   (HWSZ/THW) // 361 x-tiles per batch
#define TILE  (CCH*THW)  // 4080 elements per block

// Phase A: coalesced float4 loads along hw; transform immediately (channel is
// known per lane -> meta computed once per float4, rare channels behind
// wave-coherent branches); write results to LDS in flat output order.
// Phase B: pure LDS b128 -> global dwordx4 copy (output chunk is contiguous).
//
// R1 change: bijective XCD-aware block swizzle. Each block reads 64B per
// channel row; the 128B L2 line is split with the hw-adjacent block. Default
// dispatch round-robins adjacent blocks across the 8 non-coherent XCD L2s ->
// every line fetched twice from HBM (~2x read over-fetch). Remap so each XCD
// owns a contiguous run of hw-adjacent tiles; the shared half-line becomes a
// same-XCD L2 hit. nwg = 11552, 11552 % 8 == 0 -> swizzle is bijective.
__global__ __launch_bounds__(256) void yolo_decode_kernel(
    const float* __restrict__ x, float* __restrict__ out)
{
    __shared__ float lds[TILE];            // results, flat [hwl*255 + cc]

    const int bid = blockIdx.y * NBX + blockIdx.x;   // hardware dispatch id
    const int cpx = (NBX * 32) >> 3;                 // 11552/8 = 1444 blocks per XCD
    const int lid = (bid & 7) * cpx + (bid >> 3);    // logical id, XCD-contiguous
    const int b   = lid / NBX;                       // batch
    const int hw0 = (lid - b * NBX) * THW;           // hw tile base
    const int t   = threadIdx.x;

    const int sw = hw0 % WW;               // block-uniform grid col/row base
    const int sh = hw0 / WW;

    const float* xin = x + (size_t)b * ((size_t)CCH * HWSZ) + hw0;
    const float inv76 = 1.0f / (float)WW;

    #pragma unroll
    for (int k = 0; k < 4; ++k) {
        const int i = t + 256 * k;         // float4 index over the tile
        if (i < TILE / 4) {
            const int ch = i >> 2;         // 0..254
            const int c4 = (i & 3) << 2;   // hw sub-offset: 0,4,8,12
            const float4 v4 = *(const float4*)(xin + (size_t)ch * HWSZ + c4);

            // channel meta, once per float4:  nb = ch/85 (exact for ch<255)
            const int nb = (ch * 193) >> 14;
            const int c  = ch - nb * SKIPC;

            float a = 0.0f, bs = 1.0f, sgn = -1.0f;
            if ((unsigned)(c - 2) < 2u) {  // c==2 || c==3  (w/h channels)
                bs = 0.0f; sgn = 1.0f;
                const float aw = (nb == 0) ? 0.19078947f : ((nb == 1) ? 0.25657895f : 0.61348684f);
                const float ah = (nb == 0) ? 0.14802632f : ((nb == 1) ? 0.32565789f : 0.53618421f);
                a = (c == 2) ? aw : ah;
            }
            const bool fw = (c == 0);
            const bool fh = (c == 1);
            if (c < 2) bs = inv76;

            const float vv[4] = {v4.x, v4.y, v4.z, v4.w};
            float* dst = &lds[c4 * CCH + ch];
            #pragma unroll
            for (int e = 0; e < 4; ++e) {
                const float ev  = __expf(sgn * vv[e]);                  // v_mul + v_exp
                const float sig = __builtin_amdgcn_rcpf(1.0f + ev);     // v_add + v_rcp
                float g = 0.0f;
                if (fw | fh) {             // wave-coherent: skipped for 243/255 channels
                    const int hwl = c4 + e;
                    const int w  = sw + hwl;
                    const int wr = (w >= WW) ? (w - WW) : w;
                    const int hr = sh + ((w >= WW) ? 1 : 0);
                    g = fw ? (float)wr : (float)hr;
                }
                dst[e * CCH] = fmaf(a, ev, bs * (sig + g));
            }
        }
    }

    __syncthreads();

    // Phase B: contiguous copy-out, 16B per lane both sides.
    float* op = out + ((size_t)b * HWSZ + hw0) * (size_t)CCH;
    #pragma unroll
    for (int k = 0; k < 4; ++k) {
        const int i = t + 256 * k;
        if (i < TILE / 4) {
            const float4 v = *(const float4*)&lds[i << 2];
            *(float4*)(op + ((size_t)i << 2)) = v;
        }
    }
}

extern "C" void kernel_launch(void* const* d_in, const int* in_sizes, int n_in,
                              void* d_out, int out_size, void* d_ws, size_t ws_size,
                              hipStream_t stream) {
    const float* x = (const float*)d_in[0];
    float* out = (float*)d_out;
    const int B = in_sizes[0] / (CCH * HWSZ);   // 32
    dim3 grid(NBX, B);                          // (361, 32)
    yolo_decode_kernel<<<grid, 256, 0, stream>>>(x, out);
}

// Round 3
// 306.791 us; speedup vs baseline: 1.0274x; 1.0273x over previous
//
#include <hip/hip_runtime.h>

#define CCH   255        // NB * SKIPC
#define SKIPC 85
#define WW    76
#define HWSZ  5776       // 76*76
#define THW   16         // hw positions per block tile (5776 = 361*16)
#define NBX   (HWSZ/THW) // 361 x-tiles per batch
#define TILE  (CCH*THW)  // 4080 elements per block

typedef float floatx4 __attribute__((ext_vector_type(4)));  // native vec for nt builtins

// Phase A: coalesced float4 loads along hw; transform immediately (channel is
// known per lane -> meta computed once per float4, rare channels behind
// wave-coherent branches); write results to LDS in flat output order.
// Phase B: pure LDS b128 -> global dwordx4 copy (output chunk is contiguous).
//
// R1: bijective XCD swizzle -> NEUTRAL (L2 fetches 64B sectors; no line-split
//     over-fetch existed). Kept: harmless.
// R2/R3: nontemporal loads+stores (R3 fixes types: builtin needs native
//     ext_vector_type, not HIP_vector_type). 377 MB streamed with zero reuse;
//     default write-allocate + LLC victim churn steals BW from the stream.
__global__ __launch_bounds__(256) void yolo_decode_kernel(
    const float* __restrict__ x, float* __restrict__ out)
{
    __shared__ float lds[TILE];            // results, flat [hwl*255 + cc]

    const int bid = blockIdx.y * NBX + blockIdx.x;   // hardware dispatch id
    const int cpx = (NBX * 32) >> 3;                 // 11552/8 = 1444 blocks per XCD
    const int lid = (bid & 7) * cpx + (bid >> 3);    // logical id, XCD-contiguous
    const int b   = lid / NBX;                       // batch
    const int hw0 = (lid - b * NBX) * THW;           // hw tile base
    const int t   = threadIdx.x;

    const int sw = hw0 % WW;               // block-uniform grid col/row base
    const int sh = hw0 / WW;

    const float* xin = x + (size_t)b * ((size_t)CCH * HWSZ) + hw0;
    const float inv76 = 1.0f / (float)WW;

    #pragma unroll
    for (int k = 0; k < 4; ++k) {
        const int i = t + 256 * k;         // float4 index over the tile
        if (i < TILE / 4) {
            const int ch = i >> 2;         // 0..254
            const int c4 = (i & 3) << 2;   // hw sub-offset: 0,4,8,12
            const floatx4 v4 = __builtin_nontemporal_load(
                (const floatx4*)(xin + (size_t)ch * HWSZ + c4));

            // channel meta, once per float4:  nb = ch/85 (exact for ch<255)
            const int nb = (ch * 193) >> 14;
            const int c  = ch - nb * SKIPC;

            float a = 0.0f, bs = 1.0f, sgn = -1.0f;
            if ((unsigned)(c - 2) < 2u) {  // c==2 || c==3  (w/h channels)
                bs = 0.0f; sgn = 1.0f;
                const float aw = (nb == 0) ? 0.19078947f : ((nb == 1) ? 0.25657895f : 0.61348684f);
                const float ah = (nb == 0) ? 0.14802632f : ((nb == 1) ? 0.32565789f : 0.53618421f);
                a = (c == 2) ? aw : ah;
            }
            const bool fw = (c == 0);
            const bool fh = (c == 1);
            if (c < 2) bs = inv76;

            float* dst = &lds[c4 * CCH + ch];
            #pragma unroll
            for (int e = 0; e < 4; ++e) {
                const float ev  = __expf(sgn * v4[e]);                  // v_mul + v_exp
                const float sig = __builtin_amdgcn_rcpf(1.0f + ev);     // v_add + v_rcp
                float g = 0.0f;
                if (fw | fh) {             // wave-coherent: skipped for 243/255 channels
                    const int hwl = c4 + e;
                    const int w  = sw + hwl;
                    const int wr = (w >= WW) ? (w - WW) : w;
                    const int hr = sh + ((w >= WW) ? 1 : 0);
                    g = fw ? (float)wr : (float)hr;
                }
                dst[e * CCH] = fmaf(a, ev, bs * (sig + g));
            }
        }
    }

    __syncthreads();

    // Phase B: contiguous copy-out, 16B per lane both sides.
    float* op = out + ((size_t)b * HWSZ + hw0) * (size_t)CCH;
    #pragma unroll
    for (int k = 0; k < 4; ++k) {
        const int i = t + 256 * k;
        if (i < TILE / 4) {
            const floatx4 v = *(const floatx4*)&lds[i << 2];
            __builtin_nontemporal_store(v, (floatx4*)(op + ((size_t)i << 2)));
        }
    }
}

extern "C" void kernel_launch(void* const* d_in, const int* in_sizes, int n_in,
                              void* d_out, int out_size, void* d_ws, size_t ws_size,
                              hipStream_t stream) {
    const float* x = (const float*)d_in[0];
    float* out = (float*)d_out;
    const int B = in_sizes[0] / (CCH * HWSZ);   // 32
    dim3 grid(NBX, B);                          // (361, 32)
    yolo_decode_kernel<<<grid, 256, 0, stream>>>(x, out);
}